// Round 1
// baseline (420.095 us; speedup 1.0000x reference)
//
#include <hip/hip_runtime.h>
#include <hip/hip_bf16.h>

typedef float f32x4 __attribute__((ext_vector_type(4)));
typedef __bf16 bf16x8 __attribute__((ext_vector_type(8)));

#define H 1024
#define II 4096
#define NE 16
#define CAP 1024
#define NTOK 2048
#define NSLOT 4096

__device__ __forceinline__ void gload16(const void* g, void* l) {
  __builtin_amdgcn_global_load_lds(
      (const __attribute__((address_space(1))) unsigned*)g,
      (__attribute__((address_space(3))) unsigned*)l, 16, 0, 0);
}

// ---------------- routing: group top-2, expert top-1, weights ----------------
__global__ __launch_bounds__(256) void k_route(
    const float* __restrict__ x, const float* __restrict__ gw,
    const float* __restrict__ erw, int* __restrict__ eid,
    float* __restrict__ wgt) {
  int t = blockIdx.x * 4 + (threadIdx.x >> 6);
  int lane = threadIdx.x & 63;
  const float* xr = x + (size_t)t * H;
  double acc[20];
#pragma unroll
  for (int j = 0; j < 20; j++) acc[j] = 0.0;
  for (int it = 0; it < 16; ++it) {
    int h = it * 64 + lane;
    float xv = xr[h];
#pragma unroll
    for (int g = 0; g < 4; ++g) acc[g] += (double)xv * (double)gw[g * H + h];
#pragma unroll
    for (int j = 0; j < 16; ++j)
      acc[4 + j] += (double)xv * (double)erw[j * H + h];
  }
#pragma unroll
  for (int j = 0; j < 20; ++j) {
    double v = acc[j];
#pragma unroll
    for (int o = 32; o > 0; o >>= 1) v += __shfl_down(v, o, 64);
    acc[j] = v;
  }
  if (lane == 0) {
    float gl[4];
#pragma unroll
    for (int g = 0; g < 4; g++) gl[g] = (float)acc[g];
    int g1 = 0;
#pragma unroll
    for (int g = 1; g < 4; g++)
      if (gl[g] > gl[g1]) g1 = g;
    int g2 = (g1 == 0) ? 1 : 0;
#pragma unroll
    for (int g = 0; g < 4; g++)
      if (g != g1 && gl[g] > gl[g2]) g2 = g;
    float gm = fmaxf(fmaxf(gl[0], gl[1]), fmaxf(gl[2], gl[3]));
    float s = 0.f;
#pragma unroll
    for (int g = 0; g < 4; g++) s += expf(gl[g] - gm);
    float p[2] = {expf(gl[g1] - gm) / s, expf(gl[g2] - gm) / s};
    int gs[2] = {g1, g2};
#pragma unroll
    for (int k = 0; k < 2; k++) {
      int g = gs[k];
      float el[4];
#pragma unroll
      for (int e2 = 0; e2 < 4; e2++) el[e2] = (float)acc[4 + g * 4 + e2];
      int eb = 0;
#pragma unroll
      for (int e2 = 1; e2 < 4; e2++)
        if (el[e2] > el[eb]) eb = e2;
      float es = 0.f;
#pragma unroll
      for (int e2 = 0; e2 < 4; e2++) es += expf(el[e2] - el[eb]);
      eid[2 * t + k] = g * 4 + eb;
      wgt[2 * t + k] = p[k] * (1.f / es);
    }
  }
}

// ---------------- capacity scan: exact slot-order positions ----------------
__global__ __launch_bounds__(1024) void k_scan(const int* __restrict__ eid,
                                               int* __restrict__ perm,
                                               int* __restrict__ cnt,
                                               int* __restrict__ kept) {
  int wid = threadIdx.x >> 6;  // expert 0..15
  int lane = threadIdx.x & 63;
  int base = 0;
  for (int it = 0; it < 64; ++it) {
    int slot = it * 64 + lane;
    int e = eid[slot];
    unsigned long long m = __ballot(e == wid);
    if (e == wid) {
      int pos = base + __popcll(m & ((1ull << lane) - 1ull));
      if (pos < CAP) {
        perm[wid * CAP + pos] = slot;
        kept[slot] = 1;
      } else {
        kept[slot] = 0;
      }
    }
    base += __popcll(m);
  }
  if (lane == 0) cnt[wid] = (base < CAP) ? base : CAP;
}

// ---------------- pass 1: act = silu(x@Wg^T) * (x@Wu^T), bf16 out ----------
__global__ __launch_bounds__(256) void k_gateup(
    const float* __restrict__ x, const float* __restrict__ Wg,
    const float* __restrict__ Wu, const int* __restrict__ perm,
    const int* __restrict__ cnt, __bf16* __restrict__ act) {
  __shared__ float As[128 * 32];
  __shared__ float Gs[64 * 32];
  __shared__ float Us[64 * 32];
  __shared__ int slotArr[128];
  const int e = blockIdx.z, nt = blockIdx.x, rt = blockIdx.y;
  const int ce = cnt[e];
  if (rt * 128 >= ce) return;
  const int tid = threadIdx.x, lane = tid & 63, wid = tid >> 6;
  if (tid < 128) {
    int ridx = rt * 128 + tid;
    slotArr[tid] = perm[e * CAP + (ridx < ce ? ridx : 0)];
  }
  __syncthreads();
  int tokA[4], offA[4];
#pragma unroll
  for (int q = 0; q < 4; q++) {
    int r = wid * 32 + q * 8 + (lane >> 3);
    tokA[q] = slotArr[r] >> 1;
    offA[q] = (((lane & 7) ^ (r & 7))) * 4;  // fp32 elems
  }
  int rowW[2], offW[2];
#pragma unroll
  for (int q = 0; q < 2; q++) {
    int r = wid * 16 + q * 8 + (lane >> 3);
    rowW[q] = r;
    offW[q] = (((lane & 7) ^ (r & 7))) * 4;
  }
  const size_t ew = (size_t)e * II * H;
  const float* Wge = Wg + ew + (size_t)(nt * 64) * H;
  const float* Wue = Wu + ew + (size_t)(nt * 64) * H;
  const int wm = wid >> 1, wn = wid & 1;

  f32x4 accG[4][2], accU[4][2];
#pragma unroll
  for (int m = 0; m < 4; m++)
#pragma unroll
    for (int n = 0; n < 2; n++)
#pragma unroll
      for (int i = 0; i < 4; i++) {
        accG[m][n][i] = 0.f;
        accU[m][n][i] = 0.f;
      }

  for (int ks = 0; ks < 32; ++ks) {
    const int kb = ks * 32;
#pragma unroll
    for (int q = 0; q < 4; q++)
      gload16(x + (size_t)tokA[q] * H + kb + offA[q],
              &As[(wid * 32 + q * 8) * 32]);
#pragma unroll
    for (int q = 0; q < 2; q++) {
      gload16(Wge + (size_t)rowW[q] * H + kb + offW[q],
              &Gs[(wid * 16 + q * 8) * 32]);
      gload16(Wue + (size_t)rowW[q] * H + kb + offW[q],
              &Us[(wid * 16 + q * 8) * 32]);
    }
    __syncthreads();
    bf16x8 aF[4], gF[2], uF[2];
#pragma unroll
    for (int m = 0; m < 4; m++) {
      int r = wm * 64 + m * 16 + (lane & 15);
      int c0 = 2 * (lane >> 4);
      f32x4 lo = *(const f32x4*)&As[r * 32 + ((c0) ^ (r & 7)) * 4];
      f32x4 hi = *(const f32x4*)&As[r * 32 + ((c0 + 1) ^ (r & 7)) * 4];
      bf16x8 f;
#pragma unroll
      for (int i = 0; i < 4; i++) {
        f[i] = (__bf16)lo[i];
        f[i + 4] = (__bf16)hi[i];
      }
      aF[m] = f;
    }
#pragma unroll
    for (int n = 0; n < 2; n++) {
      int r = wn * 32 + n * 16 + (lane & 15);
      int c0 = 2 * (lane >> 4);
      {
        f32x4 lo = *(const f32x4*)&Gs[r * 32 + ((c0) ^ (r & 7)) * 4];
        f32x4 hi = *(const f32x4*)&Gs[r * 32 + ((c0 + 1) ^ (r & 7)) * 4];
        bf16x8 f;
#pragma unroll
        for (int i = 0; i < 4; i++) {
          f[i] = (__bf16)lo[i];
          f[i + 4] = (__bf16)hi[i];
        }
        gF[n] = f;
      }
      {
        f32x4 lo = *(const f32x4*)&Us[r * 32 + ((c0) ^ (r & 7)) * 4];
        f32x4 hi = *(const f32x4*)&Us[r * 32 + ((c0 + 1) ^ (r & 7)) * 4];
        bf16x8 f;
#pragma unroll
        for (int i = 0; i < 4; i++) {
          f[i] = (__bf16)lo[i];
          f[i + 4] = (__bf16)hi[i];
        }
        uF[n] = f;
      }
    }
#pragma unroll
    for (int m = 0; m < 4; m++)
#pragma unroll
      for (int n = 0; n < 2; n++) {
        accG[m][n] = __builtin_amdgcn_mfma_f32_16x16x32_bf16(aF[m], gF[n],
                                                             accG[m][n], 0, 0, 0);
        accU[m][n] = __builtin_amdgcn_mfma_f32_16x16x32_bf16(aF[m], uF[n],
                                                             accU[m][n], 0, 0, 0);
      }
    __syncthreads();
  }
  const int colB = nt * 64 + wn * 32;
#pragma unroll
  for (int m = 0; m < 4; m++)
#pragma unroll
    for (int n = 0; n < 2; n++)
#pragma unroll
      for (int i = 0; i < 4; i++) {
        int row = wm * 64 + m * 16 + (lane >> 4) * 4 + i;
        if (rt * 128 + row < ce) {
          int slot = slotArr[row];
          float g = accG[m][n][i];
          float u = accU[m][n][i];
          float a = (g / (1.f + __expf(-g))) * u;
          act[(size_t)slot * II + colB + n * 16 + (lane & 15)] = (__bf16)a;
        }
      }
}

// ---------------- pass 2: y = wgt * (act @ Wd^T) ----------------
__global__ __launch_bounds__(256) void k_down(
    const __bf16* __restrict__ act, const float* __restrict__ Wd,
    const int* __restrict__ perm, const int* __restrict__ cnt,
    const float* __restrict__ wgt, float* __restrict__ y) {
  __shared__ __bf16 As[128 * 64];
  __shared__ float Ws[64 * 64];
  __shared__ int slotArr[128];
  const int e = blockIdx.z, nt = blockIdx.x, rt = blockIdx.y;
  const int ce = cnt[e];
  if (rt * 128 >= ce) return;
  const int tid = threadIdx.x, lane = tid & 63, wid = tid >> 6;
  if (tid < 128) {
    int ridx = rt * 128 + tid;
    slotArr[tid] = perm[e * CAP + (ridx < ce ? ridx : 0)];
  }
  __syncthreads();
  int slotA[4], offA[4];
#pragma unroll
  for (int q = 0; q < 4; q++) {
    int r = wid * 32 + q * 8 + (lane >> 3);
    slotA[q] = slotArr[r];
    offA[q] = (((lane & 7) ^ (r & 7))) * 8;  // bf16 elems
  }
  int rowW[4], offW[4];
#pragma unroll
  for (int q = 0; q < 4; q++) {
    int r = wid * 16 + q * 4 + (lane >> 4);
    rowW[q] = r;
    offW[q] = (((lane & 15) ^ (r & 7))) * 4;  // fp32 elems
  }
  const float* Wde = Wd + (size_t)e * H * II + (size_t)(nt * 64) * II;
  const int wm = wid >> 1, wn = wid & 1;
  f32x4 acc[4][2];
#pragma unroll
  for (int m = 0; m < 4; m++)
#pragma unroll
    for (int n = 0; n < 2; n++)
#pragma unroll
      for (int i = 0; i < 4; i++) acc[m][n][i] = 0.f;

  for (int ks = 0; ks < 64; ++ks) {
    const int kb = ks * 64;
#pragma unroll
    for (int q = 0; q < 4; q++)
      gload16(act + (size_t)slotA[q] * II + kb + offA[q],
              &As[(wid * 32 + q * 8) * 64]);
#pragma unroll
    for (int q = 0; q < 4; q++)
      gload16(Wde + (size_t)rowW[q] * II + kb + offW[q],
              &Ws[(wid * 16 + q * 4) * 64]);
    __syncthreads();
#pragma unroll
    for (int kk = 0; kk < 2; kk++) {
      bf16x8 aF[4], wF[2];
#pragma unroll
      for (int m = 0; m < 4; m++) {
        int r = wm * 64 + m * 16 + (lane & 15);
        int c = (kk * 4 + (lane >> 4)) ^ (r & 7);
        aF[m] = *(const bf16x8*)&As[r * 64 + c * 8];
      }
#pragma unroll
      for (int n = 0; n < 2; n++) {
        int r = wn * 32 + n * 16 + (lane & 15);
        int c0 = kk * 8 + (lane >> 4) * 2;
        f32x4 lo = *(const f32x4*)&Ws[r * 64 + ((c0) ^ (r & 7)) * 4];
        f32x4 hi = *(const f32x4*)&Ws[r * 64 + ((c0 + 1) ^ (r & 7)) * 4];
        bf16x8 f;
#pragma unroll
        for (int i = 0; i < 4; i++) {
          f[i] = (__bf16)lo[i];
          f[i + 4] = (__bf16)hi[i];
        }
        wF[n] = f;
      }
#pragma unroll
      for (int m = 0; m < 4; m++)
#pragma unroll
        for (int n = 0; n < 2; n++)
          acc[m][n] = __builtin_amdgcn_mfma_f32_16x16x32_bf16(aF[m], wF[n],
                                                              acc[m][n], 0, 0, 0);
    }
    __syncthreads();
  }
  const int colB = nt * 64 + wn * 32;
#pragma unroll
  for (int m = 0; m < 4; m++)
#pragma unroll
    for (int n = 0; n < 2; n++)
#pragma unroll
      for (int i = 0; i < 4; i++) {
        int row = wm * 64 + m * 16 + (lane >> 4) * 4 + i;
        if (rt * 128 + row < ce) {
          int slot = slotArr[row];
          y[(size_t)slot * H + colB + n * 16 + (lane & 15)] =
              wgt[slot] * acc[m][n][i];
        }
      }
}

// ---------------- combine: out[t] = y[2t] + y[2t+1]; aux_loss = 0 ----------
__global__ __launch_bounds__(256) void k_combine(const float* __restrict__ y,
                                                 const int* __restrict__ kept,
                                                 float* __restrict__ out) {
  int t = blockIdx.x, tid = threadIdx.x;
  const f32x4* y0 = (const f32x4*)(y + (size_t)(2 * t) * H);
  const f32x4* y1 = (const f32x4*)(y + (size_t)(2 * t + 1) * H);
  f32x4 a, b;
#pragma unroll
  for (int i = 0; i < 4; i++) {
    a[i] = 0.f;
    b[i] = 0.f;
  }
  if (kept[2 * t]) a = y0[tid];
  if (kept[2 * t + 1]) b = y1[tid];
  ((f32x4*)out)[(size_t)t * 256 + tid] = a + b;
  if (t == 0 && tid == 0) out[(size_t)NTOK * H] = 0.f;  // aux_loss
}

extern "C" void kernel_launch(void* const* d_in, const int* in_sizes, int n_in,
                              void* d_out, int out_size, void* d_ws,
                              size_t ws_size, hipStream_t stream) {
  const float* x = (const float*)d_in[0];
  const float* gw = (const float*)d_in[1];
  const float* erw = (const float*)d_in[2];
  const float* Wg = (const float*)d_in[3];
  const float* Wu = (const float*)d_in[4];
  const float* Wd = (const float*)d_in[5];
  float* out = (float*)d_out;
  char* ws = (char*)d_ws;
  int* eid = (int*)(ws);                    // 16 KB
  float* wgt = (float*)(ws + (16 << 10));   // 16 KB
  int* kept = (int*)(ws + (32 << 10));      // 16 KB
  int* cnt = (int*)(ws + (48 << 10));       // 16 KB
  int* perm = (int*)(ws + (64 << 10));      // 64 KB
  __bf16* act = (__bf16*)(ws + (128 << 10));              // 32 MB
  float* yb = (float*)(ws + (128 << 10) + (size_t)NSLOT * II * 2);  // 16 MB

  k_route<<<NTOK / 4, 256, 0, stream>>>(x, gw, erw, eid, wgt);
  k_scan<<<1, 1024, 0, stream>>>(eid, perm, cnt, kept);
  k_gateup<<<dim3(64, 8, 16), 256, 0, stream>>>(x, Wg, Wu, perm, cnt, act);
  k_down<<<dim3(16, 8, 16), 256, 0, stream>>>(act, Wd, perm, cnt, wgt, yb);
  k_combine<<<NTOK, 256, 0, stream>>>(yb, kept, out);
}

// Round 2
// 376.652 us; speedup vs baseline: 1.1153x; 1.1153x over previous
//
#include <hip/hip_runtime.h>
#include <hip/hip_bf16.h>

typedef float f32x4 __attribute__((ext_vector_type(4)));
typedef __bf16 bf16x8 __attribute__((ext_vector_type(8)));

#define H 1024
#define II 4096
#define NE 16
#define CAP 1024
#define NTOK 2048
#define NSLOT 4096

// ---------------- routing: group top-2, expert top-1, weights ----------------
__global__ __launch_bounds__(256) void k_route(
    const float* __restrict__ x, const float* __restrict__ gw,
    const float* __restrict__ erw, int* __restrict__ eid,
    float* __restrict__ wgt) {
  int t = blockIdx.x * 4 + (threadIdx.x >> 6);
  int lane = threadIdx.x & 63;
  const float* xr = x + (size_t)t * H;
  double acc[20];
#pragma unroll
  for (int j = 0; j < 20; j++) acc[j] = 0.0;
  for (int it = 0; it < 16; ++it) {
    int h = it * 64 + lane;
    float xv = xr[h];
#pragma unroll
    for (int g = 0; g < 4; ++g) acc[g] += (double)xv * (double)gw[g * H + h];
#pragma unroll
    for (int j = 0; j < 16; ++j)
      acc[4 + j] += (double)xv * (double)erw[j * H + h];
  }
#pragma unroll
  for (int j = 0; j < 20; ++j) {
    double v = acc[j];
#pragma unroll
    for (int o = 32; o > 0; o >>= 1) v += __shfl_down(v, o, 64);
    acc[j] = v;
  }
  if (lane == 0) {
    float gl[4];
#pragma unroll
    for (int g = 0; g < 4; g++) gl[g] = (float)acc[g];
    int g1 = 0;
#pragma unroll
    for (int g = 1; g < 4; g++)
      if (gl[g] > gl[g1]) g1 = g;
    int g2 = (g1 == 0) ? 1 : 0;
#pragma unroll
    for (int g = 0; g < 4; g++)
      if (g != g1 && gl[g] > gl[g2]) g2 = g;
    float gm = fmaxf(fmaxf(gl[0], gl[1]), fmaxf(gl[2], gl[3]));
    float s = 0.f;
#pragma unroll
    for (int g = 0; g < 4; g++) s += expf(gl[g] - gm);
    float p[2] = {expf(gl[g1] - gm) / s, expf(gl[g2] - gm) / s};
    int gs[2] = {g1, g2};
#pragma unroll
    for (int k = 0; k < 2; k++) {
      int g = gs[k];
      float el[4];
#pragma unroll
      for (int e2 = 0; e2 < 4; e2++) el[e2] = (float)acc[4 + g * 4 + e2];
      int eb = 0;
#pragma unroll
      for (int e2 = 1; e2 < 4; e2++)
        if (el[e2] > el[eb]) eb = e2;
      float es = 0.f;
#pragma unroll
      for (int e2 = 0; e2 < 4; e2++) es += expf(el[e2] - el[eb]);
      eid[2 * t + k] = g * 4 + eb;
      wgt[2 * t + k] = p[k] * (1.f / es);
    }
  }
}

// ---------------- capacity scan ----------------
__global__ __launch_bounds__(1024) void k_scan(const int* __restrict__ eid,
                                               int* __restrict__ perm,
                                               int* __restrict__ cnt,
                                               int* __restrict__ kept) {
  int wid = threadIdx.x >> 6;
  int lane = threadIdx.x & 63;
  int base = 0;
  for (int it = 0; it < 64; ++it) {
    int slot = it * 64 + lane;
    int e = eid[slot];
    unsigned long long m = __ballot(e == wid);
    if (e == wid) {
      int pos = base + __popcll(m & ((1ull << lane) - 1ull));
      if (pos < CAP) {
        perm[wid * CAP + pos] = slot;
        kept[slot] = 1;
      } else {
        kept[slot] = 0;
      }
    }
    base += __popcll(m);
  }
  if (lane == 0) cnt[wid] = (base < CAP) ? base : CAP;
}

// ---------------- x -> bf16 ----------------
__global__ __launch_bounds__(256) void k_cvtx(const float* __restrict__ x,
                                              __bf16* __restrict__ xb) {
  size_t i = ((size_t)blockIdx.x * 256 + threadIdx.x) * 8;
  f32x4 a = *(const f32x4*)(x + i);
  f32x4 b = *(const f32x4*)(x + i + 4);
  bf16x8 o;
#pragma unroll
  for (int j = 0; j < 4; j++) {
    o[j] = (__bf16)a[j];
    o[j + 4] = (__bf16)b[j];
  }
  *(bf16x8*)(xb + i) = o;
}

// ---------------- pass 1: act = silu(x@Wg^T) * (x@Wu^T) ----------
// BM=128 slots, BN=64 I-cols (both G and U), BK=64, 256 thr, dbuf bf16 LDS.
__global__ __launch_bounds__(256) void k_gateup(
    const __bf16* __restrict__ xb, const float* __restrict__ Wg,
    const float* __restrict__ Wu, const int* __restrict__ perm,
    const int* __restrict__ cnt, __bf16* __restrict__ act) {
  __shared__ __bf16 As[2][128 * 64];
  __shared__ __bf16 Gs[2][64 * 64];
  __shared__ __bf16 Us[2][64 * 64];
  __shared__ int slotArr[128];
  const int e = blockIdx.z, nt = blockIdx.x, rt = blockIdx.y;
  const int ce = cnt[e];
  if (rt * 128 >= ce) return;
  const int tid = threadIdx.x, lane = tid & 63, wid = tid >> 6;
  if (tid < 128) {
    int ridx = rt * 128 + tid;
    slotArr[tid] = perm[e * CAP + (ridx < ce ? ridx : 0)];
  }
  __syncthreads();
  const int srow = tid >> 3;  // 0..31
  const int sch = tid & 7;    // 16B chunk (8 elems)
  const __bf16* pA[4];
  int wrA[4];
#pragma unroll
  for (int q = 0; q < 4; q++) {
    int r = q * 32 + srow;
    pA[q] = xb + (size_t)(slotArr[r] >> 1) * H + sch * 8;
    wrA[q] = r * 64 + (sch ^ (r & 7)) * 8;
  }
  const size_t ew = (size_t)e * II * H + (size_t)(nt * 64) * H;
  const float* pG[2];
  const float* pU[2];
  int wrW[2];
#pragma unroll
  for (int q = 0; q < 2; q++) {
    int r = q * 32 + srow;
    pG[q] = Wg + ew + (size_t)r * H + sch * 8;
    pU[q] = Wu + ew + (size_t)r * H + sch * 8;
    wrW[q] = r * 64 + (sch ^ (r & 7)) * 8;
  }
  const int wm = wid >> 1, wn = wid & 1;
  f32x4 accG[4][2], accU[4][2];
#pragma unroll
  for (int m = 0; m < 4; m++)
#pragma unroll
    for (int n = 0; n < 2; n++)
#pragma unroll
      for (int i = 0; i < 4; i++) {
        accG[m][n][i] = 0.f;
        accU[m][n][i] = 0.f;
      }
  // prologue: stage t=0 into buf 0
  {
    bf16x8 va[4];
    f32x4 g0[2], g1[2], u0[2], u1[2];
#pragma unroll
    for (int q = 0; q < 4; q++) va[q] = *(const bf16x8*)(pA[q]);
#pragma unroll
    for (int q = 0; q < 2; q++) {
      g0[q] = *(const f32x4*)(pG[q]);
      g1[q] = *(const f32x4*)(pG[q] + 4);
      u0[q] = *(const f32x4*)(pU[q]);
      u1[q] = *(const f32x4*)(pU[q] + 4);
    }
#pragma unroll
    for (int q = 0; q < 4; q++) *(bf16x8*)&As[0][wrA[q]] = va[q];
#pragma unroll
    for (int q = 0; q < 2; q++) {
      bf16x8 fg, fu;
#pragma unroll
      for (int i = 0; i < 4; i++) {
        fg[i] = (__bf16)g0[q][i];
        fg[i + 4] = (__bf16)g1[q][i];
        fu[i] = (__bf16)u0[q][i];
        fu[i + 4] = (__bf16)u1[q][i];
      }
      *(bf16x8*)&Gs[0][wrW[q]] = fg;
      *(bf16x8*)&Us[0][wrW[q]] = fu;
    }
  }
  __syncthreads();
  for (int t = 0; t < 16; ++t) {
    const int cb = t & 1, nb = cb ^ 1;
    bf16x8 va[4];
    f32x4 g0[2], g1[2], u0[2], u1[2];
    if (t < 15) {
      const int ko = (t + 1) * 64;
#pragma unroll
      for (int q = 0; q < 4; q++) va[q] = *(const bf16x8*)(pA[q] + ko);
#pragma unroll
      for (int q = 0; q < 2; q++) {
        g0[q] = *(const f32x4*)(pG[q] + ko);
        g1[q] = *(const f32x4*)(pG[q] + ko + 4);
        u0[q] = *(const f32x4*)(pU[q] + ko);
        u1[q] = *(const f32x4*)(pU[q] + ko + 4);
      }
    }
#pragma unroll
    for (int kk = 0; kk < 2; ++kk) {
      bf16x8 aF[4], gF[2], uF[2];
#pragma unroll
      for (int m = 0; m < 4; m++) {
        int r = wm * 64 + m * 16 + (lane & 15);
        int c = (kk * 4 + (lane >> 4)) ^ (r & 7);
        aF[m] = *(const bf16x8*)&As[cb][r * 64 + c * 8];
      }
#pragma unroll
      for (int n = 0; n < 2; n++) {
        int rg = wn * 32 + n * 16 + (lane & 15);
        int c = (kk * 4 + (lane >> 4)) ^ (rg & 7);
        gF[n] = *(const bf16x8*)&Gs[cb][rg * 64 + c * 8];
        uF[n] = *(const bf16x8*)&Us[cb][rg * 64 + c * 8];
      }
#pragma unroll
      for (int m = 0; m < 4; m++)
#pragma unroll
        for (int n = 0; n < 2; n++) {
          accG[m][n] = __builtin_amdgcn_mfma_f32_16x16x32_bf16(
              aF[m], gF[n], accG[m][n], 0, 0, 0);
          accU[m][n] = __builtin_amdgcn_mfma_f32_16x16x32_bf16(
              aF[m], uF[n], accU[m][n], 0, 0, 0);
        }
    }
    if (t < 15) {
#pragma unroll
      for (int q = 0; q < 4; q++) *(bf16x8*)&As[nb][wrA[q]] = va[q];
#pragma unroll
      for (int q = 0; q < 2; q++) {
        bf16x8 fg, fu;
#pragma unroll
        for (int i = 0; i < 4; i++) {
          fg[i] = (__bf16)g0[q][i];
          fg[i + 4] = (__bf16)g1[q][i];
          fu[i] = (__bf16)u0[q][i];
          fu[i + 4] = (__bf16)u1[q][i];
        }
        *(bf16x8*)&Gs[nb][wrW[q]] = fg;
        *(bf16x8*)&Us[nb][wrW[q]] = fu;
      }
    }
    __syncthreads();
  }
  const int colB = nt * 64 + wn * 32;
#pragma unroll
  for (int m = 0; m < 4; m++)
#pragma unroll
    for (int n = 0; n < 2; n++)
#pragma unroll
      for (int i = 0; i < 4; i++) {
        int row = wm * 64 + m * 16 + (lane >> 4) * 4 + i;
        if (rt * 128 + row < ce) {
          int slot = slotArr[row];
          float g = accG[m][n][i];
          float u = accU[m][n][i];
          float a = (g / (1.f + __expf(-g))) * u;
          act[(size_t)slot * II + colB + n * 16 + (lane & 15)] = (__bf16)a;
        }
      }
}

// ---------------- pass 2: y = wgt * (act @ Wd^T) ----------------
// BM=128 slots, BN=128 H-cols, BK=64, 256 thr, dbuf bf16 LDS.
__global__ __launch_bounds__(256) void k_down(
    const __bf16* __restrict__ act, const float* __restrict__ Wd,
    const int* __restrict__ perm, const int* __restrict__ cnt,
    const float* __restrict__ wgt, float* __restrict__ y) {
  __shared__ __bf16 As[2][128 * 64];
  __shared__ __bf16 Ws[2][128 * 64];
  __shared__ int slotArr[128];
  const int e = blockIdx.z, nt = blockIdx.x, rt = blockIdx.y;
  const int ce = cnt[e];
  if (rt * 128 >= ce) return;
  const int tid = threadIdx.x, lane = tid & 63, wid = tid >> 6;
  if (tid < 128) {
    int ridx = rt * 128 + tid;
    slotArr[tid] = perm[e * CAP + (ridx < ce ? ridx : 0)];
  }
  __syncthreads();
  const int srow = tid >> 3;
  const int sch = tid & 7;
  const __bf16* pA[4];
  const float* pW[4];
  int wrA[4];
#pragma unroll
  for (int q = 0; q < 4; q++) {
    int r = q * 32 + srow;
    pA[q] = act + (size_t)slotArr[r] * II + sch * 8;
    pW[q] = Wd + (size_t)e * H * II + (size_t)(nt * 128 + r) * II + sch * 8;
    wrA[q] = r * 64 + (sch ^ (r & 7)) * 8;
  }
  const int wm = wid >> 1, wn = wid & 1;
  f32x4 acc[4][4];
#pragma unroll
  for (int m = 0; m < 4; m++)
#pragma unroll
    for (int n = 0; n < 4; n++)
#pragma unroll
      for (int i = 0; i < 4; i++) acc[m][n][i] = 0.f;
  // prologue
  {
    bf16x8 va[4];
    f32x4 w0[4], w1[4];
#pragma unroll
    for (int q = 0; q < 4; q++) {
      va[q] = *(const bf16x8*)(pA[q]);
      w0[q] = *(const f32x4*)(pW[q]);
      w1[q] = *(const f32x4*)(pW[q] + 4);
    }
#pragma unroll
    for (int q = 0; q < 4; q++) {
      *(bf16x8*)&As[0][wrA[q]] = va[q];
      bf16x8 fw;
#pragma unroll
      for (int i = 0; i < 4; i++) {
        fw[i] = (__bf16)w0[q][i];
        fw[i + 4] = (__bf16)w1[q][i];
      }
      *(bf16x8*)&Ws[0][wrA[q]] = fw;
    }
  }
  __syncthreads();
  for (int t = 0; t < 64; ++t) {
    const int cb = t & 1, nb = cb ^ 1;
    bf16x8 va[4];
    f32x4 w0[4], w1[4];
    if (t < 63) {
      const int ko = (t + 1) * 64;
#pragma unroll
      for (int q = 0; q < 4; q++) {
        va[q] = *(const bf16x8*)(pA[q] + ko);
        w0[q] = *(const f32x4*)(pW[q] + ko);
        w1[q] = *(const f32x4*)(pW[q] + ko + 4);
      }
    }
#pragma unroll
    for (int kk = 0; kk < 2; ++kk) {
      bf16x8 aF[4], wF[4];
#pragma unroll
      for (int m = 0; m < 4; m++) {
        int r = wm * 64 + m * 16 + (lane & 15);
        int c = (kk * 4 + (lane >> 4)) ^ (r & 7);
        aF[m] = *(const bf16x8*)&As[cb][r * 64 + c * 8];
      }
#pragma unroll
      for (int n = 0; n < 4; n++) {
        int rw = wn * 64 + n * 16 + (lane & 15);
        int c = (kk * 4 + (lane >> 4)) ^ (rw & 7);
        wF[n] = *(const bf16x8*)&Ws[cb][rw * 64 + c * 8];
      }
#pragma unroll
      for (int m = 0; m < 4; m++)
#pragma unroll
        for (int n = 0; n < 4; n++)
          acc[m][n] = __builtin_amdgcn_mfma_f32_16x16x32_bf16(aF[m], wF[n],
                                                              acc[m][n], 0, 0, 0);
    }
    if (t < 63) {
#pragma unroll
      for (int q = 0; q < 4; q++) {
        *(bf16x8*)&As[nb][wrA[q]] = va[q];
        bf16x8 fw;
#pragma unroll
        for (int i = 0; i < 4; i++) {
          fw[i] = (__bf16)w0[q][i];
          fw[i + 4] = (__bf16)w1[q][i];
        }
        *(bf16x8*)&Ws[nb][wrA[q]] = fw;
      }
    }
    __syncthreads();
  }
  const int colB = nt * 128 + wn * 64;
#pragma unroll
  for (int m = 0; m < 4; m++)
#pragma unroll
    for (int n = 0; n < 4; n++)
#pragma unroll
      for (int i = 0; i < 4; i++) {
        int row = wm * 64 + m * 16 + (lane >> 4) * 4 + i;
        if (rt * 128 + row < ce) {
          int slot = slotArr[row];
          y[(size_t)slot * H + colB + n * 16 + (lane & 15)] =
              wgt[slot] * acc[m][n][i];
        }
      }
}

// ---------------- combine ----------
__global__ __launch_bounds__(256) void k_combine(const float* __restrict__ y,
                                                 const int* __restrict__ kept,
                                                 float* __restrict__ out) {
  int t = blockIdx.x, tid = threadIdx.x;
  const f32x4* y0 = (const f32x4*)(y + (size_t)(2 * t) * H);
  const f32x4* y1 = (const f32x4*)(y + (size_t)(2 * t + 1) * H);
  f32x4 a, b;
#pragma unroll
  for (int i = 0; i < 4; i++) {
    a[i] = 0.f;
    b[i] = 0.f;
  }
  if (kept[2 * t]) a = y0[tid];
  if (kept[2 * t + 1]) b = y1[tid];
  ((f32x4*)out)[(size_t)t * 256 + tid] = a + b;
  if (t == 0 && tid == 0) out[(size_t)NTOK * H] = 0.f;  // aux_loss
}

extern "C" void kernel_launch(void* const* d_in, const int* in_sizes, int n_in,
                              void* d_out, int out_size, void* d_ws,
                              size_t ws_size, hipStream_t stream) {
  const float* x = (const float*)d_in[0];
  const float* gw = (const float*)d_in[1];
  const float* erw = (const float*)d_in[2];
  const float* Wg = (const float*)d_in[3];
  const float* Wu = (const float*)d_in[4];
  const float* Wd = (const float*)d_in[5];
  float* out = (float*)d_out;
  char* ws = (char*)d_ws;
  int* eid = (int*)(ws);
  float* wgt = (float*)(ws + (16 << 10));
  int* kept = (int*)(ws + (32 << 10));
  int* cnt = (int*)(ws + (48 << 10));
  int* perm = (int*)(ws + (64 << 10));
  __bf16* act = (__bf16*)(ws + (128 << 10));                             // 32 MB
  float* yb = (float*)(ws + (128 << 10) + (size_t)NSLOT * II * 2);       // 16 MB
  __bf16* xb = (__bf16*)(ws + (128 << 10) + (size_t)NSLOT * II * 2 +
                         (size_t)NSLOT * H * 4);                         // 4 MB

  k_route<<<NTOK / 4, 256, 0, stream>>>(x, gw, erw, eid, wgt);
  k_scan<<<1, 1024, 0, stream>>>(eid, perm, cnt, kept);
  k_cvtx<<<NTOK * H / 8 / 256, 256, 0, stream>>>(x, xb);
  k_gateup<<<dim3(64, 8, 16), 256, 0, stream>>>(xb, Wg, Wu, perm, cnt, act);
  k_down<<<dim3(8, 8, 16), 256, 0, stream>>>(act, Wd, perm, cnt, wgt, yb);
  k_combine<<<NTOK, 256, 0, stream>>>(yb, kept, out);
}

// Round 3
// 372.532 us; speedup vs baseline: 1.1277x; 1.0111x over previous
//
#include <hip/hip_runtime.h>
#include <hip/hip_bf16.h>

typedef float f32x4 __attribute__((ext_vector_type(4)));
typedef __bf16 bf16x8 __attribute__((ext_vector_type(8)));

#define H 1024
#define II 4096
#define NE 16
#define CAP 1024
#define NTOK 2048
#define NSLOT 4096

// ---------------- routing: group top-2, expert top-1, weights ----------------
__global__ __launch_bounds__(256) void k_route(
    const float* __restrict__ x, const float* __restrict__ gw,
    const float* __restrict__ erw, int* __restrict__ eid,
    float* __restrict__ wgt) {
  int t = blockIdx.x * 4 + (threadIdx.x >> 6);
  int lane = threadIdx.x & 63;
  const float* xr = x + (size_t)t * H;
  double acc[20];
#pragma unroll
  for (int j = 0; j < 20; j++) acc[j] = 0.0;
  for (int it = 0; it < 16; ++it) {
    int h = it * 64 + lane;
    float xv = xr[h];
#pragma unroll
    for (int g = 0; g < 4; ++g) acc[g] += (double)xv * (double)gw[g * H + h];
#pragma unroll
    for (int j = 0; j < 16; ++j)
      acc[4 + j] += (double)xv * (double)erw[j * H + h];
  }
#pragma unroll
  for (int j = 0; j < 20; ++j) {
    double v = acc[j];
#pragma unroll
    for (int o = 32; o > 0; o >>= 1) v += __shfl_down(v, o, 64);
    acc[j] = v;
  }
  if (lane == 0) {
    float gl[4];
#pragma unroll
    for (int g = 0; g < 4; g++) gl[g] = (float)acc[g];
    int g1 = 0;
#pragma unroll
    for (int g = 1; g < 4; g++)
      if (gl[g] > gl[g1]) g1 = g;
    int g2 = (g1 == 0) ? 1 : 0;
#pragma unroll
    for (int g = 0; g < 4; g++)
      if (g != g1 && gl[g] > gl[g2]) g2 = g;
    float gm = fmaxf(fmaxf(gl[0], gl[1]), fmaxf(gl[2], gl[3]));
    float s = 0.f;
#pragma unroll
    for (int g = 0; g < 4; g++) s += expf(gl[g] - gm);
    float p[2] = {expf(gl[g1] - gm) / s, expf(gl[g2] - gm) / s};
    int gs[2] = {g1, g2};
#pragma unroll
    for (int k = 0; k < 2; k++) {
      int g = gs[k];
      float el[4];
#pragma unroll
      for (int e2 = 0; e2 < 4; e2++) el[e2] = (float)acc[4 + g * 4 + e2];
      int eb = 0;
#pragma unroll
      for (int e2 = 1; e2 < 4; e2++)
        if (el[e2] > el[eb]) eb = e2;
      float es = 0.f;
#pragma unroll
      for (int e2 = 0; e2 < 4; e2++) es += expf(el[e2] - el[eb]);
      eid[2 * t + k] = g * 4 + eb;
      wgt[2 * t + k] = p[k] * (1.f / es);
    }
  }
}

// ---------------- capacity scan ----------------
__global__ __launch_bounds__(1024) void k_scan(const int* __restrict__ eid,
                                               int* __restrict__ perm,
                                               int* __restrict__ cnt,
                                               int* __restrict__ kept) {
  int wid = threadIdx.x >> 6;
  int lane = threadIdx.x & 63;
  int base = 0;
  for (int it = 0; it < 64; ++it) {
    int slot = it * 64 + lane;
    int e = eid[slot];
    unsigned long long m = __ballot(e == wid);
    if (e == wid) {
      int pos = base + __popcll(m & ((1ull << lane) - 1ull));
      if (pos < CAP) {
        perm[wid * CAP + pos] = slot;
        kept[slot] = 1;
      } else {
        kept[slot] = 0;
      }
    }
    base += __popcll(m);
  }
  if (lane == 0) cnt[wid] = (base < CAP) ? base : CAP;
}

// ---------------- x -> bf16 ----------------
__global__ __launch_bounds__(256) void k_cvtx(const float* __restrict__ x,
                                              __bf16* __restrict__ xb) {
  size_t i = ((size_t)blockIdx.x * 256 + threadIdx.x) * 8;
  f32x4 a = *(const f32x4*)(x + i);
  f32x4 b = *(const f32x4*)(x + i + 4);
  bf16x8 o;
#pragma unroll
  for (int j = 0; j < 4; j++) {
    o[j] = (__bf16)a[j];
    o[j + 4] = (__bf16)b[j];
  }
  *(bf16x8*)(xb + i) = o;
}

#define FENCE_BAR()                                    \
  asm volatile("s_waitcnt lgkmcnt(0)" ::: "memory");   \
  __builtin_amdgcn_sched_barrier(0);                   \
  __builtin_amdgcn_s_barrier();

// ---------------- pass 1: act = silu(x@Wg^T) * (x@Wu^T) ----------
// BM=128 slots, BN=64 I-cols (G and U), BK=64, 256 thr, 2-deep reg pipeline.
__global__ __launch_bounds__(256, 2) void k_gateup(
    const __bf16* __restrict__ xb, const float* __restrict__ Wg,
    const float* __restrict__ Wu, const int* __restrict__ perm,
    const int* __restrict__ cnt, __bf16* __restrict__ act) {
  __shared__ __bf16 As[2][128 * 64];
  __shared__ __bf16 Gs[2][64 * 64];
  __shared__ __bf16 Us[2][64 * 64];
  __shared__ int slotArr[128];
  const int e = blockIdx.z, nt = blockIdx.x, rt = blockIdx.y;
  const int ce = cnt[e];
  if (rt * 128 >= ce) return;
  const int tid = threadIdx.x, lane = tid & 63, wid = tid >> 6;
  if (tid < 128) {
    int ridx = rt * 128 + tid;
    slotArr[tid] = perm[e * CAP + (ridx < ce ? ridx : 0)];
  }
  __syncthreads();
  const int srow = tid >> 3;  // 0..31
  const int sch = tid & 7;    // 16B chunk
  const __bf16* pA[4];
  int wrA[4];
#pragma unroll
  for (int q = 0; q < 4; q++) {
    int r = q * 32 + srow;
    pA[q] = xb + (size_t)(slotArr[r] >> 1) * H + sch * 8;
    wrA[q] = r * 64 + (sch ^ (r & 7)) * 8;
  }
  const size_t ew = (size_t)e * II * H + (size_t)(nt * 64) * H;
  const float* pG[2];
  const float* pU[2];
  int wrW[2];
#pragma unroll
  for (int q = 0; q < 2; q++) {
    int r = q * 32 + srow;
    pG[q] = Wg + ew + (size_t)r * H + sch * 8;
    pU[q] = Wu + ew + (size_t)r * H + sch * 8;
    wrW[q] = r * 64 + (sch ^ (r & 7)) * 8;
  }
  const int wm = wid >> 1, wn = wid & 1;
  f32x4 accG[4][2], accU[4][2];
#pragma unroll
  for (int m = 0; m < 4; m++)
#pragma unroll
    for (int n = 0; n < 2; n++)
#pragma unroll
      for (int i = 0; i < 4; i++) {
        accG[m][n][i] = 0.f;
        accU[m][n][i] = 0.f;
      }
  bf16x8 a0[4], a1[4];
  f32x4 g00[2], g01[2], u00[2], u01[2];
  f32x4 g10[2], g11[2], u10[2], u11[2];

#define GU_LOADS(AS, G0, G1, U0, U1, T)                                    \
  {                                                                        \
    const int ko = (T) * 64;                                               \
    _Pragma("unroll") for (int q = 0; q < 4; q++)                          \
        AS[q] = *(const bf16x8*)(pA[q] + ko);                              \
    _Pragma("unroll") for (int q = 0; q < 2; q++) {                        \
      G0[q] = *(const f32x4*)(pG[q] + ko);                                 \
      G1[q] = *(const f32x4*)(pG[q] + ko + 4);                             \
      U0[q] = *(const f32x4*)(pU[q] + ko);                                 \
      U1[q] = *(const f32x4*)(pU[q] + ko + 4);                             \
    }                                                                      \
  }
#define GU_WRITE(BUF, AS, G0, G1, U0, U1)                                  \
  {                                                                        \
    _Pragma("unroll") for (int q = 0; q < 4; q++)                          \
        *(bf16x8*)&As[BUF][wrA[q]] = AS[q];                                \
    _Pragma("unroll") for (int q = 0; q < 2; q++) {                        \
      bf16x8 fg, fu;                                                       \
      _Pragma("unroll") for (int i = 0; i < 4; i++) {                      \
        fg[i] = (__bf16)G0[q][i];                                          \
        fg[i + 4] = (__bf16)G1[q][i];                                      \
        fu[i] = (__bf16)U0[q][i];                                          \
        fu[i + 4] = (__bf16)U1[q][i];                                      \
      }                                                                    \
      *(bf16x8*)&Gs[BUF][wrW[q]] = fg;                                     \
      *(bf16x8*)&Us[BUF][wrW[q]] = fu;                                     \
    }                                                                      \
  }
#define GU_COMPUTE(BUF)                                                    \
  {                                                                        \
    _Pragma("unroll") for (int kk = 0; kk < 2; ++kk) {                     \
      bf16x8 aF[4], gF[2], uF[2];                                          \
      _Pragma("unroll") for (int m = 0; m < 4; m++) {                      \
        int r = wm * 64 + m * 16 + (lane & 15);                            \
        int c = (kk * 4 + (lane >> 4)) ^ (r & 7);                          \
        aF[m] = *(const bf16x8*)&As[BUF][r * 64 + c * 8];                  \
      }                                                                    \
      _Pragma("unroll") for (int n = 0; n < 2; n++) {                      \
        int rg = wn * 32 + n * 16 + (lane & 15);                           \
        int c = (kk * 4 + (lane >> 4)) ^ (rg & 7);                         \
        gF[n] = *(const bf16x8*)&Gs[BUF][rg * 64 + c * 8];                 \
        uF[n] = *(const bf16x8*)&Us[BUF][rg * 64 + c * 8];                 \
      }                                                                    \
      _Pragma("unroll") for (int m = 0; m < 4; m++)                        \
          _Pragma("unroll") for (int n = 0; n < 2; n++) {                  \
        accG[m][n] = __builtin_amdgcn_mfma_f32_16x16x32_bf16(              \
            aF[m], gF[n], accG[m][n], 0, 0, 0);                            \
        accU[m][n] = __builtin_amdgcn_mfma_f32_16x16x32_bf16(              \
            aF[m], uF[n], accU[m][n], 0, 0, 0);                            \
      }                                                                    \
    }                                                                      \
  }

  GU_LOADS(a0, g00, g01, u00, u01, 0);
  GU_LOADS(a1, g10, g11, u10, u11, 1);
  GU_WRITE(0, a0, g00, g01, u00, u01);
  FENCE_BAR();
  for (int tt = 0; tt < 8; ++tt) {
    const int t0 = 2 * tt;
    if (t0 + 2 < 16) GU_LOADS(a0, g00, g01, u00, u01, t0 + 2);
    GU_COMPUTE(0);
    GU_WRITE(1, a1, g10, g11, u10, u11);
    FENCE_BAR();
    const int t1 = t0 + 1;
    if (t1 + 2 < 16) GU_LOADS(a1, g10, g11, u10, u11, t1 + 2);
    GU_COMPUTE(1);
    if (t1 + 1 < 16) {
      GU_WRITE(0, a0, g00, g01, u00, u01);
      FENCE_BAR();
    }
  }
  const int colB = nt * 64 + wn * 32;
#pragma unroll
  for (int m = 0; m < 4; m++)
#pragma unroll
    for (int n = 0; n < 2; n++)
#pragma unroll
      for (int i = 0; i < 4; i++) {
        int row = wm * 64 + m * 16 + (lane >> 4) * 4 + i;
        if (rt * 128 + row < ce) {
          int slot = slotArr[row];
          float g = accG[m][n][i];
          float u = accU[m][n][i];
          float a = (g / (1.f + __expf(-g))) * u;
          act[(size_t)slot * II + colB + n * 16 + (lane & 15)] = (__bf16)a;
        }
      }
}

// ---------------- pass 2: y = wgt * (act @ Wd^T) ----------------
// BM=128 slots, BN=64 H-cols, BK=64, 256 thr, 2-deep reg pipeline.
__global__ __launch_bounds__(256, 2) void k_down(
    const __bf16* __restrict__ act, const float* __restrict__ Wd,
    const int* __restrict__ perm, const int* __restrict__ cnt,
    const float* __restrict__ wgt, float* __restrict__ y) {
  __shared__ __bf16 As[2][128 * 64];
  __shared__ __bf16 Ws[2][64 * 64];
  __shared__ int slotArr[128];
  const int e = blockIdx.z, nt = blockIdx.x, rt = blockIdx.y;
  const int ce = cnt[e];
  if (rt * 128 >= ce) return;
  const int tid = threadIdx.x, lane = tid & 63, wid = tid >> 6;
  if (tid < 128) {
    int ridx = rt * 128 + tid;
    slotArr[tid] = perm[e * CAP + (ridx < ce ? ridx : 0)];
  }
  __syncthreads();
  const int srow = tid >> 3;
  const int sch = tid & 7;
  const __bf16* pA[4];
  int wrA[4];
#pragma unroll
  for (int q = 0; q < 4; q++) {
    int r = q * 32 + srow;
    pA[q] = act + (size_t)slotArr[r] * II + sch * 8;
    wrA[q] = r * 64 + (sch ^ (r & 7)) * 8;
  }
  const float* pW[2];
  int wrW[2];
#pragma unroll
  for (int q = 0; q < 2; q++) {
    int r = q * 32 + srow;
    pW[q] = Wd + (size_t)e * H * II + (size_t)(nt * 64 + r) * II + sch * 8;
    wrW[q] = r * 64 + (sch ^ (r & 7)) * 8;
  }
  const int wm = wid >> 1, wn = wid & 1;
  f32x4 acc[4][2];
#pragma unroll
  for (int m = 0; m < 4; m++)
#pragma unroll
    for (int n = 0; n < 2; n++)
#pragma unroll
      for (int i = 0; i < 4; i++) acc[m][n][i] = 0.f;
  bf16x8 a0[4], a1[4];
  f32x4 w00[2], w01[2], w10[2], w11[2];

#define DN_LOADS(AS, W0, W1, T)                                            \
  {                                                                        \
    const int ko = (T) * 64;                                               \
    _Pragma("unroll") for (int q = 0; q < 4; q++)                          \
        AS[q] = *(const bf16x8*)(pA[q] + ko);                              \
    _Pragma("unroll") for (int q = 0; q < 2; q++) {                        \
      W0[q] = *(const f32x4*)(pW[q] + ko);                                 \
      W1[q] = *(const f32x4*)(pW[q] + ko + 4);                             \
    }                                                                      \
  }
#define DN_WRITE(BUF, AS, W0, W1)                                          \
  {                                                                        \
    _Pragma("unroll") for (int q = 0; q < 4; q++)                          \
        *(bf16x8*)&As[BUF][wrA[q]] = AS[q];                                \
    _Pragma("unroll") for (int q = 0; q < 2; q++) {                        \
      bf16x8 fw;                                                           \
      _Pragma("unroll") for (int i = 0; i < 4; i++) {                      \
        fw[i] = (__bf16)W0[q][i];                                          \
        fw[i + 4] = (__bf16)W1[q][i];                                      \
      }                                                                    \
      *(bf16x8*)&Ws[BUF][wrW[q]] = fw;                                     \
    }                                                                      \
  }
#define DN_COMPUTE(BUF)                                                    \
  {                                                                        \
    _Pragma("unroll") for (int kk = 0; kk < 2; ++kk) {                     \
      bf16x8 aF[4], wF[2];                                                 \
      _Pragma("unroll") for (int m = 0; m < 4; m++) {                      \
        int r = wm * 64 + m * 16 + (lane & 15);                            \
        int c = (kk * 4 + (lane >> 4)) ^ (r & 7);                          \
        aF[m] = *(const bf16x8*)&As[BUF][r * 64 + c * 8];                  \
      }                                                                    \
      _Pragma("unroll") for (int n = 0; n < 2; n++) {                      \
        int rw = wn * 32 + n * 16 + (lane & 15);                           \
        int c = (kk * 4 + (lane >> 4)) ^ (rw & 7);                         \
        wF[n] = *(const bf16x8*)&Ws[BUF][rw * 64 + c * 8];                 \
      }                                                                    \
      _Pragma("unroll") for (int m = 0; m < 4; m++)                        \
          _Pragma("unroll") for (int n = 0; n < 2; n++)                    \
              acc[m][n] = __builtin_amdgcn_mfma_f32_16x16x32_bf16(         \
                  aF[m], wF[n], acc[m][n], 0, 0, 0);                       \
    }                                                                      \
  }

  DN_LOADS(a0, w00, w01, 0);
  DN_LOADS(a1, w10, w11, 1);
  DN_WRITE(0, a0, w00, w01);
  FENCE_BAR();
  for (int tt = 0; tt < 32; ++tt) {
    const int t0 = 2 * tt;
    if (t0 + 2 < 64) DN_LOADS(a0, w00, w01, t0 + 2);
    DN_COMPUTE(0);
    DN_WRITE(1, a1, w10, w11);
    FENCE_BAR();
    const int t1 = t0 + 1;
    if (t1 + 2 < 64) DN_LOADS(a1, w10, w11, t1 + 2);
    DN_COMPUTE(1);
    if (t1 + 1 < 64) {
      DN_WRITE(0, a0, w00, w01);
      FENCE_BAR();
    }
  }
  const int colB = nt * 64 + wn * 32;
#pragma unroll
  for (int m = 0; m < 4; m++)
#pragma unroll
    for (int n = 0; n < 2; n++)
#pragma unroll
      for (int i = 0; i < 4; i++) {
        int row = wm * 64 + m * 16 + (lane >> 4) * 4 + i;
        if (rt * 128 + row < ce) {
          int slot = slotArr[row];
          y[(size_t)slot * H + colB + n * 16 + (lane & 15)] =
              wgt[slot] * acc[m][n][i];
        }
      }
}

// ---------------- combine ----------
__global__ __launch_bounds__(256) void k_combine(const float* __restrict__ y,
                                                 const int* __restrict__ kept,
                                                 float* __restrict__ out) {
  int t = blockIdx.x, tid = threadIdx.x;
  const f32x4* y0 = (const f32x4*)(y + (size_t)(2 * t) * H);
  const f32x4* y1 = (const f32x4*)(y + (size_t)(2 * t + 1) * H);
  f32x4 a, b;
#pragma unroll
  for (int i = 0; i < 4; i++) {
    a[i] = 0.f;
    b[i] = 0.f;
  }
  if (kept[2 * t]) a = y0[tid];
  if (kept[2 * t + 1]) b = y1[tid];
  ((f32x4*)out)[(size_t)t * 256 + tid] = a + b;
  if (t == 0 && tid == 0) out[(size_t)NTOK * H] = 0.f;  // aux_loss
}

extern "C" void kernel_launch(void* const* d_in, const int* in_sizes, int n_in,
                              void* d_out, int out_size, void* d_ws,
                              size_t ws_size, hipStream_t stream) {
  const float* x = (const float*)d_in[0];
  const float* gw = (const float*)d_in[1];
  const float* erw = (const float*)d_in[2];
  const float* Wg = (const float*)d_in[3];
  const float* Wu = (const float*)d_in[4];
  const float* Wd = (const float*)d_in[5];
  float* out = (float*)d_out;
  char* ws = (char*)d_ws;
  int* eid = (int*)(ws);
  float* wgt = (float*)(ws + (16 << 10));
  int* kept = (int*)(ws + (32 << 10));
  int* cnt = (int*)(ws + (48 << 10));
  int* perm = (int*)(ws + (64 << 10));
  __bf16* act = (__bf16*)(ws + (128 << 10));                             // 32 MB
  float* yb = (float*)(ws + (128 << 10) + (size_t)NSLOT * II * 2);       // 16 MB
  __bf16* xb = (__bf16*)(ws + (128 << 10) + (size_t)NSLOT * II * 2 +
                         (size_t)NSLOT * H * 4);                         // 4 MB

  k_route<<<NTOK / 4, 256, 0, stream>>>(x, gw, erw, eid, wgt);
  k_scan<<<1, 1024, 0, stream>>>(eid, perm, cnt, kept);
  k_cvtx<<<NTOK * H / 8 / 256, 256, 0, stream>>>(x, xb);
  k_gateup<<<dim3(64, 8, 16), 256, 0, stream>>>(xb, Wg, Wu, perm, cnt, act);
  k_down<<<dim3(16, 8, 16), 256, 0, stream>>>(act, Wd, perm, cnt, wgt, yb);
  k_combine<<<NTOK, 256, 0, stream>>>(yb, kept, out);
}

// Round 4
// 371.803 us; speedup vs baseline: 1.1299x; 1.0020x over previous
//
#include <hip/hip_runtime.h>
#include <hip/hip_bf16.h>

typedef float f32x4 __attribute__((ext_vector_type(4)));
typedef __bf16 bf16x8 __attribute__((ext_vector_type(8)));

#define H 1024
#define II 4096
#define NE 16
#define CAP 1024
#define NTOK 2048
#define NSLOT 4096

// ---------------- routing: group top-2, expert top-1, weights ----------------
__global__ __launch_bounds__(256) void k_route(
    const float* __restrict__ x, const float* __restrict__ gw,
    const float* __restrict__ erw, int* __restrict__ eid,
    float* __restrict__ wgt) {
  int t = blockIdx.x * 4 + (threadIdx.x >> 6);
  int lane = threadIdx.x & 63;
  const float* xr = x + (size_t)t * H;
  double acc[20];
#pragma unroll
  for (int j = 0; j < 20; j++) acc[j] = 0.0;
  for (int it = 0; it < 16; ++it) {
    int h = it * 64 + lane;
    float xv = xr[h];
#pragma unroll
    for (int g = 0; g < 4; ++g) acc[g] += (double)xv * (double)gw[g * H + h];
#pragma unroll
    for (int j = 0; j < 16; ++j)
      acc[4 + j] += (double)xv * (double)erw[j * H + h];
  }
#pragma unroll
  for (int j = 0; j < 20; ++j) {
    double v = acc[j];
#pragma unroll
    for (int o = 32; o > 0; o >>= 1) v += __shfl_down(v, o, 64);
    acc[j] = v;
  }
  if (lane == 0) {
    float gl[4];
#pragma unroll
    for (int g = 0; g < 4; g++) gl[g] = (float)acc[g];
    int g1 = 0;
#pragma unroll
    for (int g = 1; g < 4; g++)
      if (gl[g] > gl[g1]) g1 = g;
    int g2 = (g1 == 0) ? 1 : 0;
#pragma unroll
    for (int g = 0; g < 4; g++)
      if (g != g1 && gl[g] > gl[g2]) g2 = g;
    float gm = fmaxf(fmaxf(gl[0], gl[1]), fmaxf(gl[2], gl[3]));
    float s = 0.f;
#pragma unroll
    for (int g = 0; g < 4; g++) s += expf(gl[g] - gm);
    float p[2] = {expf(gl[g1] - gm) / s, expf(gl[g2] - gm) / s};
    int gs[2] = {g1, g2};
#pragma unroll
    for (int k = 0; k < 2; k++) {
      int g = gs[k];
      float el[4];
#pragma unroll
      for (int e2 = 0; e2 < 4; e2++) el[e2] = (float)acc[4 + g * 4 + e2];
      int eb = 0;
#pragma unroll
      for (int e2 = 1; e2 < 4; e2++)
        if (el[e2] > el[eb]) eb = e2;
      float es = 0.f;
#pragma unroll
      for (int e2 = 0; e2 < 4; e2++) es += expf(el[e2] - el[eb]);
      eid[2 * t + k] = g * 4 + eb;
      wgt[2 * t + k] = p[k] * (1.f / es);
    }
  }
}

// ---------------- capacity scan ----------------
__global__ __launch_bounds__(1024) void k_scan(const int* __restrict__ eid,
                                               int* __restrict__ perm,
                                               int* __restrict__ cnt,
                                               int* __restrict__ kept) {
  int wid = threadIdx.x >> 6;
  int lane = threadIdx.x & 63;
  int base = 0;
  for (int it = 0; it < 64; ++it) {
    int slot = it * 64 + lane;
    int e = eid[slot];
    unsigned long long m = __ballot(e == wid);
    if (e == wid) {
      int pos = base + __popcll(m & ((1ull << lane) - 1ull));
      if (pos < CAP) {
        perm[wid * CAP + pos] = slot;
        kept[slot] = 1;
      } else {
        kept[slot] = 0;
      }
    }
    base += __popcll(m);
  }
  if (lane == 0) cnt[wid] = (base < CAP) ? base : CAP;
}

// ---------------- x -> bf16 ----------------
__global__ __launch_bounds__(256) void k_cvtx(const float* __restrict__ x,
                                              __bf16* __restrict__ xb) {
  size_t i = ((size_t)blockIdx.x * 256 + threadIdx.x) * 8;
  f32x4 a = *(const f32x4*)(x + i);
  f32x4 b = *(const f32x4*)(x + i + 4);
  bf16x8 o;
#pragma unroll
  for (int j = 0; j < 4; j++) {
    o[j] = (__bf16)a[j];
    o[j + 4] = (__bf16)b[j];
  }
  *(bf16x8*)(xb + i) = o;
}

#define FENCE_BAR()                                    \
  asm volatile("s_waitcnt lgkmcnt(0)" ::: "memory");   \
  __builtin_amdgcn_sched_barrier(0);                   \
  __builtin_amdgcn_s_barrier();

// ---------------- pass 1: act = silu(x@Wg^T) * (x@Wu^T) ----------
// BM=128 slots, 128 I-cols for G AND U (256 N-rows staged), BK=32,
// 512 thr (8 waves, 4m x 2n), single-buffer LDS, 2-deep reg pipeline.
__global__ __launch_bounds__(512, 2) void k_gateup(
    const __bf16* __restrict__ xb, const float* __restrict__ Wg,
    const float* __restrict__ Wu, const int* __restrict__ perm,
    const int* __restrict__ cnt, __bf16* __restrict__ act) {
  __shared__ __bf16 As[128 * 32];
  __shared__ __bf16 Gs[128 * 32];
  __shared__ __bf16 Us[128 * 32];
  __shared__ int slotArr[128];
  const int e = blockIdx.z, nt = blockIdx.x, rt = blockIdx.y;
  const int ce = cnt[e];
  if (rt * 128 >= ce) return;
  const int tid = threadIdx.x, lane = tid & 63, wid = tid >> 6;
  if (tid < 128) {
    int ridx = rt * 128 + tid;
    slotArr[tid] = perm[e * CAP + (ridx < ce ? ridx : 0)];
  }
  __syncthreads();
  // staging role: one 8-elem chunk per tile per thread
  const int srow = tid >> 2;  // 0..127
  const int sch = tid & 3;    // chunk
  const int wrOff = srow * 32 + (sch ^ ((srow >> 1) & 3)) * 8;
  const __bf16* pA = xb + (size_t)(slotArr[srow] >> 1) * H + sch * 8;
  const size_t ew = (size_t)e * II * H + (size_t)(nt * 128 + srow) * H;
  const float* pG = Wg + ew + sch * 8;
  const float* pU = Wu + ew + sch * 8;
  const int wm = wid >> 1, wn = wid & 1;
  f32x4 accG[2][4], accU[2][4];
#pragma unroll
  for (int m = 0; m < 2; m++)
#pragma unroll
    for (int n = 0; n < 4; n++)
#pragma unroll
      for (int i = 0; i < 4; i++) {
        accG[m][n][i] = 0.f;
        accU[m][n][i] = 0.f;
      }
  bf16x8 sA0, sA1;
  f32x4 sG00, sG01, sU00, sU01, sG10, sG11, sU10, sU11;

#define GU_LOADS(A8, G0, G1, U0, U1, T)     \
  {                                         \
    const int ko = (T) * 32;                \
    A8 = *(const bf16x8*)(pA + ko);         \
    G0 = *(const f32x4*)(pG + ko);          \
    G1 = *(const f32x4*)(pG + ko + 4);      \
    U0 = *(const f32x4*)(pU + ko);          \
    U1 = *(const f32x4*)(pU + ko + 4);      \
  }
#define GU_WRITE(A8, G0, G1, U0, U1)        \
  {                                         \
    *(bf16x8*)&As[wrOff] = A8;              \
    bf16x8 fg, fu;                          \
    _Pragma("unroll") for (int i = 0; i < 4; i++) { \
      fg[i] = (__bf16)G0[i];                \
      fg[i + 4] = (__bf16)G1[i];            \
      fu[i] = (__bf16)U0[i];                \
      fu[i + 4] = (__bf16)U1[i];            \
    }                                       \
    *(bf16x8*)&Gs[wrOff] = fg;              \
    *(bf16x8*)&Us[wrOff] = fu;              \
  }
#define GU_COMPUTE()                                                     \
  {                                                                      \
    bf16x8 aF[2], gF[4], uF[4];                                          \
    _Pragma("unroll") for (int m = 0; m < 2; m++) {                      \
      int r = wm * 32 + m * 16 + (lane & 15);                            \
      int c = (lane >> 4) ^ ((r >> 1) & 3);                              \
      aF[m] = *(const bf16x8*)&As[r * 32 + c * 8];                       \
    }                                                                    \
    _Pragma("unroll") for (int n = 0; n < 4; n++) {                      \
      int r = wn * 64 + n * 16 + (lane & 15);                            \
      int c = (lane >> 4) ^ ((r >> 1) & 3);                              \
      gF[n] = *(const bf16x8*)&Gs[r * 32 + c * 8];                       \
      uF[n] = *(const bf16x8*)&Us[r * 32 + c * 8];                       \
    }                                                                    \
    _Pragma("unroll") for (int m = 0; m < 2; m++)                        \
        _Pragma("unroll") for (int n = 0; n < 4; n++) {                  \
      accG[m][n] = __builtin_amdgcn_mfma_f32_16x16x32_bf16(              \
          aF[m], gF[n], accG[m][n], 0, 0, 0);                            \
      accU[m][n] = __builtin_amdgcn_mfma_f32_16x16x32_bf16(              \
          aF[m], uF[n], accU[m][n], 0, 0, 0);                            \
    }                                                                    \
  }

  GU_LOADS(sA0, sG00, sG01, sU00, sU01, 0);
  GU_LOADS(sA1, sG10, sG11, sU10, sU11, 1);
  GU_WRITE(sA0, sG00, sG01, sU00, sU01);
  FENCE_BAR();
  for (int tt = 0; tt < 16; ++tt) {
    const int t0 = 2 * tt;
    if (t0 + 2 < 32) GU_LOADS(sA0, sG00, sG01, sU00, sU01, t0 + 2);
    GU_COMPUTE();
    FENCE_BAR();
    GU_WRITE(sA1, sG10, sG11, sU10, sU11);
    FENCE_BAR();
    if (t0 + 3 < 32) GU_LOADS(sA1, sG10, sG11, sU10, sU11, t0 + 3);
    GU_COMPUTE();
    if (t0 + 2 < 32) {
      FENCE_BAR();
      GU_WRITE(sA0, sG00, sG01, sU00, sU01);
      FENCE_BAR();
    }
  }
  const int colB = nt * 128 + wn * 64;
#pragma unroll
  for (int m = 0; m < 2; m++)
#pragma unroll
    for (int n = 0; n < 4; n++)
#pragma unroll
      for (int i = 0; i < 4; i++) {
        int row = wm * 32 + m * 16 + (lane >> 4) * 4 + i;
        if (rt * 128 + row < ce) {
          int slot = slotArr[row];
          float g = accG[m][n][i];
          float u = accU[m][n][i];
          float a = (g / (1.f + __expf(-g))) * u;
          act[(size_t)slot * II + colB + n * 16 + (lane & 15)] = (__bf16)a;
        }
      }
}

// ---------------- pass 2: y = wgt * (act @ Wd^T) ----------------
// BM=128 slots, BN=128 H-cols, BK=64, 512 thr (4m x 2n), single-buf LDS.
__global__ __launch_bounds__(512, 2) void k_down(
    const __bf16* __restrict__ act, const float* __restrict__ Wd,
    const int* __restrict__ perm, const int* __restrict__ cnt,
    const float* __restrict__ wgt, float* __restrict__ y) {
  __shared__ __bf16 As[128 * 64];
  __shared__ __bf16 Ws[128 * 64];
  __shared__ int slotArr[128];
  const int e = blockIdx.z, nt = blockIdx.x, rt = blockIdx.y;
  const int ce = cnt[e];
  if (rt * 128 >= ce) return;
  const int tid = threadIdx.x, lane = tid & 63, wid = tid >> 6;
  if (tid < 128) {
    int ridx = rt * 128 + tid;
    slotArr[tid] = perm[e * CAP + (ridx < ce ? ridx : 0)];
  }
  __syncthreads();
  const int srow = tid >> 2;  // 0..127
  const int c0 = tid & 3;     // chunks c0 and c0+4
  const int wr0 = srow * 64 + (c0 ^ (srow & 7)) * 8;
  const int wr1 = srow * 64 + ((c0 + 4) ^ (srow & 7)) * 8;
  const __bf16* pA = act + (size_t)slotArr[srow] * II + c0 * 8;
  const float* pW =
      Wd + (size_t)e * H * II + (size_t)(nt * 128 + srow) * II + c0 * 8;
  const int wm = wid >> 1, wn = wid & 1;
  f32x4 acc[2][4];
#pragma unroll
  for (int m = 0; m < 2; m++)
#pragma unroll
    for (int n = 0; n < 4; n++)
#pragma unroll
      for (int i = 0; i < 4; i++) acc[m][n][i] = 0.f;
  bf16x8 dA00, dA01, dA10, dA11;
  f32x4 dW000, dW001, dW010, dW011, dW100, dW101, dW110, dW111;

#define DN_LOADS(A0, A1, W00, W01, W10, W11, T) \
  {                                             \
    const int ko = (T) * 64;                    \
    A0 = *(const bf16x8*)(pA + ko);             \
    A1 = *(const bf16x8*)(pA + ko + 32);        \
    W00 = *(const f32x4*)(pW + ko);             \
    W01 = *(const f32x4*)(pW + ko + 4);         \
    W10 = *(const f32x4*)(pW + ko + 32);        \
    W11 = *(const f32x4*)(pW + ko + 36);        \
  }
#define DN_WRITE(A0, A1, W00, W01, W10, W11)    \
  {                                             \
    *(bf16x8*)&As[wr0] = A0;                    \
    *(bf16x8*)&As[wr1] = A1;                    \
    bf16x8 f0, f1;                              \
    _Pragma("unroll") for (int i = 0; i < 4; i++) { \
      f0[i] = (__bf16)W00[i];                   \
      f0[i + 4] = (__bf16)W01[i];               \
      f1[i] = (__bf16)W10[i];                   \
      f1[i + 4] = (__bf16)W11[i];               \
    }                                           \
    *(bf16x8*)&Ws[wr0] = f0;                    \
    *(bf16x8*)&Ws[wr1] = f1;                    \
  }
#define DN_COMPUTE()                                                     \
  {                                                                      \
    _Pragma("unroll") for (int kk = 0; kk < 2; ++kk) {                   \
      bf16x8 aF[2], wF[4];                                               \
      _Pragma("unroll") for (int m = 0; m < 2; m++) {                    \
        int r = wm * 32 + m * 16 + (lane & 15);                          \
        int c = (kk * 4 + (lane >> 4)) ^ (r & 7);                        \
        aF[m] = *(const bf16x8*)&As[r * 64 + c * 8];                     \
      }                                                                  \
      _Pragma("unroll") for (int n = 0; n < 4; n++) {                    \
        int r = wn * 64 + n * 16 + (lane & 15);                          \
        int c = (kk * 4 + (lane >> 4)) ^ (r & 7);                        \
        wF[n] = *(const bf16x8*)&Ws[r * 64 + c * 8];                     \
      }                                                                  \
      _Pragma("unroll") for (int m = 0; m < 2; m++)                      \
          _Pragma("unroll") for (int n = 0; n < 4; n++)                  \
              acc[m][n] = __builtin_amdgcn_mfma_f32_16x16x32_bf16(       \
                  aF[m], wF[n], acc[m][n], 0, 0, 0);                     \
    }                                                                    \
  }

  DN_LOADS(dA00, dA01, dW000, dW001, dW010, dW011, 0);
  DN_LOADS(dA10, dA11, dW100, dW101, dW110, dW111, 1);
  DN_WRITE(dA00, dA01, dW000, dW001, dW010, dW011);
  FENCE_BAR();
  for (int tt = 0; tt < 32; ++tt) {
    const int t0 = 2 * tt;
    if (t0 + 2 < 64) DN_LOADS(dA00, dA01, dW000, dW001, dW010, dW011, t0 + 2);
    DN_COMPUTE();
    FENCE_BAR();
    DN_WRITE(dA10, dA11, dW100, dW101, dW110, dW111);
    FENCE_BAR();
    if (t0 + 3 < 64) DN_LOADS(dA10, dA11, dW100, dW101, dW110, dW111, t0 + 3);
    DN_COMPUTE();
    if (t0 + 2 < 64) {
      FENCE_BAR();
      DN_WRITE(dA00, dA01, dW000, dW001, dW010, dW011);
      FENCE_BAR();
    }
  }
  const int colB = nt * 128 + wn * 64;
#pragma unroll
  for (int m = 0; m < 2; m++)
#pragma unroll
    for (int n = 0; n < 4; n++)
#pragma unroll
      for (int i = 0; i < 4; i++) {
        int row = wm * 32 + m * 16 + (lane >> 4) * 4 + i;
        if (rt * 128 + row < ce) {
          int slot = slotArr[row];
          y[(size_t)slot * H + colB + n * 16 + (lane & 15)] =
              wgt[slot] * acc[m][n][i];
        }
      }
}

// ---------------- combine ----------
__global__ __launch_bounds__(256) void k_combine(const float* __restrict__ y,
                                                 const int* __restrict__ kept,
                                                 float* __restrict__ out) {
  int t = blockIdx.x, tid = threadIdx.x;
  const f32x4* y0 = (const f32x4*)(y + (size_t)(2 * t) * H);
  const f32x4* y1 = (const f32x4*)(y + (size_t)(2 * t + 1) * H);
  f32x4 a, b;
#pragma unroll
  for (int i = 0; i < 4; i++) {
    a[i] = 0.f;
    b[i] = 0.f;
  }
  if (kept[2 * t]) a = y0[tid];
  if (kept[2 * t + 1]) b = y1[tid];
  ((f32x4*)out)[(size_t)t * 256 + tid] = a + b;
  if (t == 0 && tid == 0) out[(size_t)NTOK * H] = 0.f;  // aux_loss
}

extern "C" void kernel_launch(void* const* d_in, const int* in_sizes, int n_in,
                              void* d_out, int out_size, void* d_ws,
                              size_t ws_size, hipStream_t stream) {
  const float* x = (const float*)d_in[0];
  const float* gw = (const float*)d_in[1];
  const float* erw = (const float*)d_in[2];
  const float* Wg = (const float*)d_in[3];
  const float* Wu = (const float*)d_in[4];
  const float* Wd = (const float*)d_in[5];
  float* out = (float*)d_out;
  char* ws = (char*)d_ws;
  int* eid = (int*)(ws);
  float* wgt = (float*)(ws + (16 << 10));
  int* kept = (int*)(ws + (32 << 10));
  int* cnt = (int*)(ws + (48 << 10));
  int* perm = (int*)(ws + (64 << 10));
  __bf16* act = (__bf16*)(ws + (128 << 10));                             // 32 MB
  float* yb = (float*)(ws + (128 << 10) + (size_t)NSLOT * II * 2);       // 16 MB
  __bf16* xb = (__bf16*)(ws + (128 << 10) + (size_t)NSLOT * II * 2 +
                         (size_t)NSLOT * H * 4);                         // 4 MB

  k_route<<<NTOK / 4, 256, 0, stream>>>(x, gw, erw, eid, wgt);
  k_scan<<<1, 1024, 0, stream>>>(eid, perm, cnt, kept);
  k_cvtx<<<NTOK * H / 8 / 256, 256, 0, stream>>>(x, xb);
  k_gateup<<<dim3(32, 8, 16), 512, 0, stream>>>(xb, Wg, Wu, perm, cnt, act);
  k_down<<<dim3(8, 8, 16), 512, 0, stream>>>(act, Wd, perm, cnt, wgt, yb);
  k_combine<<<NTOK, 256, 0, stream>>>(yb, kept, out);
}